// Round 7
// baseline (689.526 us; speedup 1.0000x reference)
//
#include <hip/hip_runtime.h>
#include <hip/hip_bf16.h>

#define N_NODES 100000
#define N_EDGES 1600000
#define DIM_IN  256
#define DIM_H   128

typedef __attribute__((ext_vector_type(8))) short short8;
typedef __attribute__((ext_vector_type(4))) float f32x4;

// ---------------- width detect + zero (deg, acc1, acc2) merged ----------
__global__ __launch_bounds__(1024)
void k_init(const int* __restrict__ e, int* __restrict__ flag,
            int* __restrict__ deg, float* __restrict__ z1,
            float* __restrict__ z2) {
  if (blockIdx.x == 0) {
    __shared__ int s;
    if (threadIdx.x == 0) s = 0;
    __syncthreads();
    atomicOr(&s, e[2 * threadIdx.x + 1]);
    __syncthreads();
    if (threadIdx.x == 0) *flag = (s == 0) ? 1 : 0;
  } else {
    int i = (blockIdx.x - 1) * 1024 + threadIdx.x;
    if (i < N_NODES) deg[i] = 0;
    if (i < 4 * N_NODES) z1[i] = 0.f;   // acc1: N x float4
    if (i < 2 * N_NODES) z2[i] = 0.f;   // acc2: N x float2
  }
}

// ---------------- degree count: reads ONLY the dst row (12.8 MB) --------
__global__ __launch_bounds__(256)
void k_degc(const int* __restrict__ eidx, const int* __restrict__ flag,
            int* __restrict__ deg) {
  int i = blockIdx.x * 256 + threadIdx.x;
  if (i >= N_EDGES) return;
  const int is64 = *flag;
  unsigned s, d;
  if (is64) {
    s = (unsigned)((const int2*)eidx)[i].x;
    d = (unsigned)((const int2*)eidx)[N_EDGES + i].x;
  } else {
    s = (unsigned)eidx[i];
    d = (unsigned)eidx[N_EDGES + i];
  }
  if (s < N_NODES && d < N_NODES) atomicAdd(&deg[d], 1);
}

// ---------------------------------------------------------------- bf16 utils
__device__ __forceinline__ ushort f2bf(float f) {
  unsigned u = __float_as_uint(f);
  unsigned r = (u + 0x7fffu + ((u >> 16) & 1u)) >> 16;
  return (ushort)r;
}
__device__ __forceinline__ float bf2f(ushort h) {
  return __uint_as_float(((unsigned)h) << 16);
}

__device__ __forceinline__ void load8(const float* p, float* o) {
  float4 a = reinterpret_cast<const float4*>(p)[0];
  float4 b = reinterpret_cast<const float4*>(p)[1];
  o[0] = a.x; o[1] = a.y; o[2] = a.z; o[3] = a.w;
  o[4] = b.x; o[5] = b.y; o[6] = b.z; o[7] = b.w;
}

__device__ __forceinline__ void cvt_split(const float* v, short8& h, short8& l) {
#pragma unroll
  for (int j = 0; j < 8; ++j) {
    ushort hb = f2bf(v[j]);
    ushort lb = f2bf(v[j] - bf2f(hb));
    h[j] = (short)hb;
    l[j] = (short)lb;
  }
}

// Blocks 0..15: split Wi[256x128] into MFMA B-fragment planes (hi, lo).
// Block 16: fully collapsed tail weights
//   Wcc = W1 @ (W2 @ Wh)  [128 x 2]   (everything after h1 is linear)
//   c1  = b1 @ (W2 @ Wh)  [2]         stored at Wcc[256..257]
//   bc  = b2 @ Wh + bh    [2]         stored at Wcc[258..259]
__global__ __launch_bounds__(256)
void k_prep(const float* __restrict__ Wi, const float* __restrict__ W1,
            const float* __restrict__ W2, const float* __restrict__ Wh,
            const float* __restrict__ b1, const float* __restrict__ b2,
            const float* __restrict__ bh, ushort* __restrict__ outHi,
            float* __restrict__ Wcc) {
  __shared__ float Wc2s[DIM_H][2];
  constexpr int CH = DIM_IN / 32;   // 8
  if (blockIdx.x == 16) {
    const int t = threadIdx.x;
    const int i = t >> 1, j = t & 1;
    float s = 0.f;
#pragma unroll 4
    for (int m = 0; m < DIM_H; ++m) s += W2[(size_t)i * DIM_H + m] * Wh[m * 2 + j];
    Wc2s[i][j] = s;
    __syncthreads();
    float c = 0.f;
#pragma unroll 4
    for (int k = 0; k < DIM_H; ++k) c += W1[(size_t)i * DIM_H + k] * Wc2s[k][j];
    Wcc[i * 2 + j] = c;
    if (t < 2) {
      float a = 0.f, b = 0.f;
      for (int k = 0; k < DIM_H; ++k) {
        a += b1[k] * Wc2s[k][t];
        b += b2[k] * Wh[k * 2 + t];
      }
      Wcc[256 + t] = a;           // c1
      Wcc[258 + t] = b + bh[t];   // bc
    }
    return;
  }
  int idx = blockIdx.x * 256 + threadIdx.x;   // < CH*512 = 4096
  int n  = idx & 15;
  int qq = (idx >> 4) & 3;
  int nt = (idx >> 6) & 7;
  int c  = idx >> 9;
  int col = nt * 16 + n;
  short8 h8, l8;
#pragma unroll
  for (int j = 0; j < 8; ++j) {
    float v = Wi[(size_t)(c * 32 + qq * 8 + j) * DIM_H + col];
    ushort hb = f2bf(v);
    ushort lb = f2bf(v - bf2f(hb));
    h8[j] = (short)hb;
    l8[j] = (short)lb;
  }
  ((short8*)outHi)[idx] = h8;
  ((short8*)outHi)[CH * 512 + idx] = l8;
}

// ------------- Cooperative MFMA GEMM, 64-row tile, double-buffered LDS with
// XOR-swizzled staging (bank-conflict-free writes AND reads), one barrier per
// K-step, A+B prefetch into registers; fused z = relu(.)@Wcc epilogue.
// 4 waves: each wave = 4 m-tiles x 2 col-tiles (24 MFMA / K-step).
// Swizzle: granule(row,q) = (row>>4)*64 + q*16 + ((row&15) ^ (q<<2)).
// Emits tbl[row] = (dinv*z0, dinv*z1, dinv, 0); dinv = rsqrt(1+deg) inline.
template <int K>
__global__ __launch_bounds__(256, 4)
void k_gemm_xz(const float* __restrict__ A, const ushort* __restrict__ Bfrag,
               const float* __restrict__ bias, const float* __restrict__ Wcc,
               const int* __restrict__ deg, float4* __restrict__ tbl) {
  constexpr int CH = K / 32;   // 8
  __shared__ __align__(16) ushort AhiS[2][256 * 8];   // 8 KB x2 buf
  __shared__ __align__(16) ushort AloS[2][256 * 8];
  const int tid = threadIdx.x;
  const int m0 = blockIdx.x * 64;
  const int wave = tid >> 6, lane = tid & 63;
  const int m_l = lane & 15, quad = lane >> 4;
  const int rs = tid >> 2, q = tid & 3;

  f32x4 acc[2][4];
#pragma unroll
  for (int i = 0; i < 2; ++i)
#pragma unroll
    for (int j = 0; j < 4; ++j) acc[i][j] = (f32x4){0.f, 0.f, 0.f, 0.f};

  const short8* Bhi8 = (const short8*)Bfrag;
  const short8* Blo8 = Bhi8 + CH * 512;
  short8* Ah = (short8*)AhiS;
  short8* Al = (short8*)AloS;

  // each thread stages one (row, k-granule): row = rs (0..63), q = granule
  const int gr = m0 + rs;
  const float* Ap = &A[(size_t)((gr < N_NODES) ? gr : (N_NODES - 1)) * K + q * 8];
  const int went = (rs >> 4) * 64 + q * 16 + ((rs & 15) ^ (q << 2));   // swizzled write
  const int rent = quad * 16 + (m_l ^ (quad << 2));                     // + mt*64 on read

  // prologue: stage c=0 into buf 0; preload B for c=0
  {
    float v[8];
    load8(Ap, v);
    short8 h, l;
    cvt_split(v, h, l);
    Ah[went] = h;
    Al[went] = l;
  }
  const int bq = quad * 16 + m_l;
  short8 bh0 = Bhi8[(wave * 2 + 0) * 64 + bq];
  short8 bl0 = Blo8[(wave * 2 + 0) * 64 + bq];
  short8 bh1 = Bhi8[(wave * 2 + 1) * 64 + bq];
  short8 bl1 = Blo8[(wave * 2 + 1) * 64 + bq];
  __syncthreads();

#pragma unroll
  for (int c = 0; c < CH; ++c) {
    const int cur = c & 1, nxt = cur ^ 1;
    // prefetch next K-chunk (A) and next B fragments into registers
    float vn[8];
    short8 nbh0, nbl0, nbh1, nbl1;
    if (c + 1 < CH) {
      load8(Ap + (c + 1) * 32, vn);
      const int b0 = ((c + 1) * 8 + wave * 2 + 0) * 64 + bq;
      const int b1 = ((c + 1) * 8 + wave * 2 + 1) * 64 + bq;
      nbh0 = Bhi8[b0]; nbl0 = Blo8[b0];
      nbh1 = Bhi8[b1]; nbl1 = Blo8[b1];
    }
    const short8* AhC = Ah + cur * 256;
    const short8* AlC = Al + cur * 256;
#pragma unroll
    for (int mt = 0; mt < 4; ++mt) {
      short8 ahi = AhC[mt * 64 + rent];
      short8 alo = AlC[mt * 64 + rent];
      acc[0][mt] = __builtin_amdgcn_mfma_f32_16x16x32_bf16(ahi, bh0, acc[0][mt], 0, 0, 0);
      acc[0][mt] = __builtin_amdgcn_mfma_f32_16x16x32_bf16(ahi, bl0, acc[0][mt], 0, 0, 0);
      acc[0][mt] = __builtin_amdgcn_mfma_f32_16x16x32_bf16(alo, bh0, acc[0][mt], 0, 0, 0);
      acc[1][mt] = __builtin_amdgcn_mfma_f32_16x16x32_bf16(ahi, bh1, acc[1][mt], 0, 0, 0);
      acc[1][mt] = __builtin_amdgcn_mfma_f32_16x16x32_bf16(ahi, bl1, acc[1][mt], 0, 0, 0);
      acc[1][mt] = __builtin_amdgcn_mfma_f32_16x16x32_bf16(alo, bh1, acc[1][mt], 0, 0, 0);
    }
    // convert + store next chunk into the other buffer; rotate B regs
    if (c + 1 < CH) {
      short8 h, l;
      cvt_split(vn, h, l);
      Ah[nxt * 256 + went] = h;
      Al[nxt * 256 + went] = l;
      bh0 = nbh0; bl0 = nbl0; bh1 = nbh1; bl1 = nbl1;
    }
    __syncthreads();
  }

  // ---- fused epilogue: p = relu(acc + bias) @ Wcc, reduced over 128 cols
  float p0[4][4], p1[4][4];
#pragma unroll
  for (int mt = 0; mt < 4; ++mt)
#pragma unroll
    for (int r = 0; r < 4; ++r) { p0[mt][r] = 0.f; p1[mt][r] = 0.f; }
#pragma unroll
  for (int ntl = 0; ntl < 2; ++ntl) {
    const int colg = (wave * 2 + ntl) * 16 + m_l;
    const float bv = bias[colg];
    const float w0 = Wcc[colg * 2 + 0];
    const float w1 = Wcc[colg * 2 + 1];
#pragma unroll
    for (int mt = 0; mt < 4; ++mt)
#pragma unroll
      for (int r = 0; r < 4; ++r) {
        float hv = fmaxf(acc[ntl][mt][r] + bv, 0.f);   // relu(h1)
        p0[mt][r] += hv * w0;
        p1[mt][r] += hv * w1;
      }
  }
  // reduce across the 16 m_l lanes (columns); stays within the quad group
#pragma unroll
  for (int o = 1; o < 16; o <<= 1) {
#pragma unroll
    for (int mt = 0; mt < 4; ++mt)
#pragma unroll
      for (int r = 0; r < 4; ++r) {
        p0[mt][r] += __shfl_xor(p0[mt][r], o);
        p1[mt][r] += __shfl_xor(p1[mt][r], o);
      }
  }
  // cross-wave reduction via LDS (staging dead after final barrier above)
  float* zred = (float*)AhiS;   // [j][wave][quad][mt][r] = [2][4][4][4][4]
  if (m_l == 0) {
#pragma unroll
    for (int mt = 0; mt < 4; ++mt)
#pragma unroll
      for (int r = 0; r < 4; ++r) {
        zred[(((0 * 4 + wave) * 4 + quad) * 4 + mt) * 4 + r] = p0[mt][r];
        zred[(((1 * 4 + wave) * 4 + quad) * 4 + mt) * 4 + r] = p1[mt][r];
      }
  }
  __syncthreads();
  if (tid < 64) {
    // row-in-block = mt*16 + quad*4 + r == tid
    const int mt = tid >> 4, qd = (tid >> 2) & 3, r = tid & 3;
    const int rowg = m0 + tid;
    if (rowg < N_NODES) {
      float s0 = 0.f, s1 = 0.f;
#pragma unroll
      for (int w = 0; w < 4; ++w) {
        s0 += zred[(((0 * 4 + w) * 4 + qd) * 4 + mt) * 4 + r];
        s1 += zred[(((1 * 4 + w) * 4 + qd) * 4 + mt) * 4 + r];
      }
      float dn = rsqrtf(1.0f + (float)deg[rowg]);
      tbl[rowg] = make_float4(dn * s0, dn * s1, dn, 0.f);
    }
  }
}

// ---------------- pass 1 scatter: acc1[d] += tbl[s]  (xyz, L2 atomics) ----
__global__ __launch_bounds__(256)
void k_scat1(const int* __restrict__ eidx, const int* __restrict__ flag,
             const float4* __restrict__ tbl, float4* __restrict__ acc1) {
  int i = blockIdx.x * 256 + threadIdx.x;
  if (i >= N_EDGES) return;
  const int is64 = *flag;
  unsigned s, d;
  if (is64) {
    s = (unsigned)((const int2*)eidx)[i].x;
    d = (unsigned)((const int2*)eidx)[N_EDGES + i].x;
  } else {
    s = (unsigned)eidx[i];
    d = (unsigned)eidx[N_EDGES + i];
  }
  if (s < N_NODES && d < N_NODES) {
    float4 t = tbl[s];
    float* a = (float*)(acc1 + d);
    unsafeAtomicAdd(a + 0, t.x);
    unsafeAtomicAdd(a + 1, t.y);
    unsafeAtomicAdd(a + 2, t.z);
  }
}

// ---------------- finalize 1: yt[d] = dinv²·(z[d]+Σz[s]); g = dinv·Σdinv ---
__global__ __launch_bounds__(256)
void k_fin1(const float4* __restrict__ acc1, const float4* __restrict__ tbl,
            float2* __restrict__ tb2, float* __restrict__ g) {
  int n = blockIdx.x * 256 + threadIdx.x;
  if (n >= N_NODES) return;
  float4 a = acc1[n];
  float4 t = tbl[n];
  float dn = t.z;
  tb2[n] = make_float2(dn * dn * (a.x + t.x), dn * dn * (a.y + t.y));
  g[n] = dn * (a.z + t.z);
}

// ---------------- pass 2 scatter: acc2[d] += tb2[s]  (xy, L2 atomics) -----
__global__ __launch_bounds__(256)
void k_scat2(const int* __restrict__ eidx, const int* __restrict__ flag,
             const float2* __restrict__ tb2, float2* __restrict__ acc2) {
  int i = blockIdx.x * 256 + threadIdx.x;
  if (i >= N_EDGES) return;
  const int is64 = *flag;
  unsigned s, d;
  if (is64) {
    s = (unsigned)((const int2*)eidx)[i].x;
    d = (unsigned)((const int2*)eidx)[N_EDGES + i].x;
  } else {
    s = (unsigned)eidx[i];
    d = (unsigned)eidx[N_EDGES + i];
  }
  if (s < N_NODES && d < N_NODES) {
    float2 t = tb2[s];
    float* a = (float*)(acc2 + d);
    unsafeAtomicAdd(a + 0, t.x);
    unsafeAtomicAdd(a + 1, t.y);
  }
}

// ---------------- finalize 2: out = bc + dinv·(yt+Σyt) + g·c1 -------------
// tail = {c1[0],c1[1],bc[0],bc[1]}
__global__ __launch_bounds__(256)
void k_fin2(const float2* __restrict__ acc2, const float2* __restrict__ tb2,
            const float4* __restrict__ tbl, const float* __restrict__ g,
            const float* __restrict__ tail, float* __restrict__ out) {
  int n = blockIdx.x * 256 + threadIdx.x;
  if (n >= N_NODES) return;
  float2 a = acc2[n];
  float2 y = tb2[n];
  float dn = tbl[n].z;
  float gv = g[n];
  float o0 = dn * (y.x + a.x) + gv * tail[0] + tail[2];
  float o1 = dn * (y.y + a.y) + gv * tail[1] + tail[3];
  reinterpret_cast<float2*>(out)[n] = make_float2(o0, o1);
}

// --------------------------------------------- fp32 fallback (small ws) ----
__global__ __launch_bounds__(256) void k_count(const int* __restrict__ eidx,
                                               const int* __restrict__ flag,
                                               int* __restrict__ off) {
  int e = blockIdx.x * 256 + threadIdx.x;
  int is64 = *flag;
  if (e < N_EDGES) {
    unsigned d = is64 ? (unsigned)((const int2*)eidx)[N_EDGES + e].x
                      : (unsigned)eidx[N_EDGES + e];
    if (d < N_NODES) atomicAdd(&off[d], 1);
  }
}

__global__ __launch_bounds__(256) void k_dinv_old(const int* __restrict__ off,
                                                  float* __restrict__ dinv) {
  int i = blockIdx.x * 256 + threadIdx.x;
  if (i < N_NODES) dinv[i] = rsqrtf(1.0f + (float)off[i]);
}

template <int K>
__global__ __launch_bounds__(256)
void k_gemm(const float* __restrict__ A, const float* __restrict__ B,
            const float* __restrict__ bias, const float* __restrict__ scale,
            float* __restrict__ C, const int do_relu) {
  __shared__ float As[64][33];
  const int tid = threadIdx.x;
  const int tx = tid & 15;
  const int ty = tid >> 4;
  const int m0 = blockIdx.x * 64;

  float acc[4][8];
#pragma unroll
  for (int i = 0; i < 4; ++i)
#pragma unroll
    for (int j = 0; j < 8; ++j) acc[i][j] = 0.f;

  const int rs = tid >> 2;
  const int ks = (tid & 3) * 8;

  for (int k0 = 0; k0 < K; k0 += 32) {
    float av8[8];
    const int gm = m0 + rs;
    if (gm < N_NODES) {
      load8(&A[(size_t)gm * K + k0 + ks], av8);
    } else {
#pragma unroll
      for (int j = 0; j < 8; ++j) av8[j] = 0.f;
    }
    __syncthreads();
#pragma unroll
    for (int j = 0; j < 8; ++j) As[rs][ks + j] = av8[j];
    __syncthreads();

    const float* Bp = B + (size_t)k0 * DIM_H + tx * 8;
#pragma unroll 4
    for (int k = 0; k < 32; ++k) {
      float bv[8];
      load8(Bp + (size_t)k * DIM_H, bv);
      float av[4];
#pragma unroll
      for (int rr = 0; rr < 4; ++rr) av[rr] = As[ty * 4 + rr][k];
#pragma unroll
      for (int rr = 0; rr < 4; ++rr)
#pragma unroll
        for (int cc = 0; cc < 8; ++cc)
          acc[rr][cc] = fmaf(av[rr], bv[cc], acc[rr][cc]);
    }
  }

  float bs[8];
  if (bias) {
    load8(bias + tx * 8, bs);
  } else {
#pragma unroll
    for (int j = 0; j < 8; ++j) bs[j] = 0.f;
  }
#pragma unroll
  for (int rr = 0; rr < 4; ++rr) {
    const int gm = m0 + ty * 4 + rr;
    if (gm < N_NODES) {
      float sc = scale ? scale[gm] : 1.0f;
      float v[8];
#pragma unroll
      for (int cc = 0; cc < 8; ++cc) {
        float t = acc[rr][cc] + bs[cc];
        if (do_relu) t = fmaxf(t, 0.f);
        v[cc] = t * sc;
      }
      float* Cp = &C[(size_t)gm * DIM_H + tx * 8];
      reinterpret_cast<float4*>(Cp)[0] = make_float4(v[0], v[1], v[2], v[3]);
      reinterpret_cast<float4*>(Cp)[1] = make_float4(v[4], v[5], v[6], v[7]);
    }
  }
}

__global__ __launch_bounds__(256)
void k_aggr_init(const float* __restrict__ t, const float* __restrict__ dinv,
                 const float* __restrict__ bias, float* __restrict__ h) {
  int idx = blockIdx.x * 256 + threadIdx.x;
  if (idx < N_NODES * DIM_H) {
    int i = idx >> 7;
    int c = idx & 127;
    float d = dinv[i];
    h[idx] = bias[c] + t[idx] * d * d;
  }
}

__global__ __launch_bounds__(256)
void k_aggr_edges(const int* __restrict__ eidx, const int* __restrict__ flag,
                  const float* __restrict__ t, const float* __restrict__ dinv,
                  float* __restrict__ h) {
  int e = blockIdx.x * 2 + (threadIdx.x >> 7);
  int c = threadIdx.x & 127;
  int is64 = *flag;
  if (e < N_EDGES) {
    unsigned s = is64 ? (unsigned)((const int2*)eidx)[e].x : (unsigned)eidx[e];
    unsigned d = is64 ? (unsigned)((const int2*)eidx)[N_EDGES + e].x
                      : (unsigned)eidx[N_EDGES + e];
    if (s < N_NODES && d < N_NODES) {
      float nrm = dinv[s] * dinv[d];
      unsafeAtomicAdd(&h[(size_t)d * DIM_H + c], t[(size_t)s * DIM_H + c] * nrm);
    }
  }
}

__global__ __launch_bounds__(256)
void k_head_f32(const float* __restrict__ h, const float* __restrict__ Wh,
                const float* __restrict__ bh, float* __restrict__ out) {
  int node = blockIdx.x * 4 + (threadIdx.x >> 6);
  int lane = threadIdx.x & 63;
  if (node >= N_NODES) return;
  float h0 = h[(size_t)node * DIM_H + lane];
  float h1 = h[(size_t)node * DIM_H + 64 + lane];
  float s0 = h0 * Wh[lane * 2 + 0] + h1 * Wh[(lane + 64) * 2 + 0];
  float s1 = h0 * Wh[lane * 2 + 1] + h1 * Wh[(lane + 64) * 2 + 1];
#pragma unroll
  for (int off = 32; off > 0; off >>= 1) {
    s0 += __shfl_down(s0, off);
    s1 += __shfl_down(s1, off);
  }
  if (lane == 0) {
    reinterpret_cast<float2*>(out)[node] = make_float2(s0 + bh[0], s1 + bh[1]);
  }
}

// ---------------------------------------------------------------- launch
extern "C" void kernel_launch(void* const* d_in, const int* in_sizes, int n_in,
                              void* d_out, int out_size, void* d_ws, size_t ws_size,
                              hipStream_t stream) {
  (void)in_sizes; (void)n_in; (void)out_size;
  const int* eidx = (const int*)d_in[0];
  const float* x  = (const float*)d_in[1];
  const float* Wi = (const float*)d_in[2];
  const float* bi = (const float*)d_in[3];
  const float* W1 = (const float*)d_in[4];
  const float* b1 = (const float*)d_in[5];
  const float* W2 = (const float*)d_in[6];
  const float* b2 = (const float*)d_in[7];
  const float* Wh = (const float*)d_in[8];
  const float* bh = (const float*)d_in[9];
  float* out = (float*)d_out;

  const int gE  = (N_EDGES + 255) / 256;     // 6250
  const int gM  = (N_NODES + 63) / 64;       // 1563
  const int gW  = (N_NODES + 3) / 4;
  const int gN256 = (N_NODES + 255) / 256;   // 391
  const int gZ  = 1 + (4 * N_NODES + 1023) / 1024;   // 392 (init+zero)

  char* ws = (char*)d_ws;
  int* flag = (int*)ws;

  const size_t need1 = 5739264;

  if (ws_size >= need1) {
    float*  Wcc  = (float*)(ws + 4096);       // 260 floats
    ushort* bfWi = (ushort*)(ws + 8192);      // 131072 B -> end 139264
    int*    deg  = (int*)(ws + 139264);       // 400000 B -> end 539264
    float4* tbl  = (float4*)(ws + 539264);    // 1600000 B -> end 2139264
    float4* acc1 = (float4*)(ws + 2139264);   // 1600000 B -> end 3739264
    float2* tb2  = (float2*)(ws + 3739264);   // 800000 B -> end 4539264
    float*  g    = (float*)(ws + 4539264);    // 400000 B -> end 4939264
    float2* acc2 = (float2*)(ws + 4939264);   // 800000 B -> end 5739264

    // detect + zero accumulators; degree count (dst row only)
    k_init<<<gZ, 1024, 0, stream>>>(eidx, flag, deg, (float*)acc1, (float*)acc2);
    k_degc<<<gE, 256, 0, stream>>>(eidx, flag, deg);

    // weight prep: Wi fragments + collapsed tail Wcc = W1@W2@Wh (merged)
    k_prep<<<17, 256, 0, stream>>>(Wi, W1, W2, Wh, b1, b2, bh, bfWi, Wcc);

    // z = relu(x@Wi+bi) @ Wcc fused into GEMM epilogue -> tbl (N x float4)
    k_gemm_xz<DIM_IN><<<gM, 256, 0, stream>>>(x, bfWi, bi, Wcc, deg, tbl);

    // edge-centric scatter aggregation (tables L2-resident; no CSR build)
    k_scat1<<<gE, 256, 0, stream>>>(eidx, flag, tbl, acc1);
    k_fin1<<<gN256, 256, 0, stream>>>(acc1, tbl, tb2, g);
    k_scat2<<<gE, 256, 0, stream>>>(eidx, flag, tb2, acc2);
    k_fin2<<<gN256, 256, 0, stream>>>(acc2, tb2, tbl, g, Wcc + 256, out);
  } else {
    // fallback: fp32 atomic-scatter path (~103 MB)
    int*   off  = (int*)(ws + 4096);
    float* dinv = (float*)(ws + 404480);
    float* fbA  = (float*)(ws + 804864);
    float* fbB  = (float*)(ws + 804864 + (size_t)N_NODES * DIM_H * 4);
    const int gNH = (N_NODES * DIM_H + 255) / 256;
    const int gE2 = (N_EDGES + 1) / 2;
    // k_init zeroes off[0..N) plus scratch in fbA/fbB (overwritten later)
    k_init<<<gZ, 1024, 0, stream>>>(eidx, flag, off, fbA, fbB);
    k_count<<<gE, 256, 0, stream>>>(eidx, flag, off);
    k_dinv_old<<<gN256, 256, 0, stream>>>(off, dinv);

    k_gemm<DIM_IN><<<gM, 256, 0, stream>>>(x, Wi, bi, nullptr, fbA, 1);
    k_gemm<DIM_H><<<gM, 256, 0, stream>>>(fbA, W1, nullptr, nullptr, fbB, 0);
    k_aggr_init<<<gNH, 256, 0, stream>>>(fbB, dinv, b1, fbA);
    k_aggr_edges<<<gE2, 256, 0, stream>>>(eidx, flag, fbB, dinv, fbA);
    k_gemm<DIM_H><<<gM, 256, 0, stream>>>(fbA, W2, nullptr, nullptr, fbB, 0);
    k_aggr_init<<<gNH, 256, 0, stream>>>(fbB, dinv, b2, fbA);
    k_aggr_edges<<<gE2, 256, 0, stream>>>(eidx, flag, fbB, dinv, fbA);
    k_head_f32<<<gW, 256, 0, stream>>>(fbA, Wh, bh, out);
  }
}

// Round 8
// 291.212 us; speedup vs baseline: 2.3678x; 2.3678x over previous
//
#include <hip/hip_runtime.h>
#include <hip/hip_bf16.h>

#define N_NODES 100000
#define N_EDGES 1600000
#define DIM_IN  256
#define DIM_H   128

#define NBKT 782          // ceil(N_NODES / 128) buckets of 128 nodes
#define CPAD 16           // ints per padded counter (one cacheline)
#define CAP  4096         // records per bucket (mean 2048, sd ~45 -> safe)
#define EPB  8192         // edges per build block
#define NBLK ((N_EDGES + EPB - 1) / EPB)   // 196

typedef __attribute__((ext_vector_type(8))) short short8;
typedef __attribute__((ext_vector_type(4))) float f32x4;

__device__ __forceinline__ int get_src(const int* e, int is64, int i) {
  return is64 ? e[2 * i] : e[i];
}
__device__ __forceinline__ int get_dst(const int* e, int is64, int i) {
  return is64 ? e[2 * (N_EDGES + i)] : e[N_EDGES + i];
}

// ---------------------------------------------------------------- bf16 utils
__device__ __forceinline__ ushort f2bf(float f) {
  unsigned u = __float_as_uint(f);
  unsigned r = (u + 0x7fffu + ((u >> 16) & 1u)) >> 16;
  return (ushort)r;
}
__device__ __forceinline__ float bf2f(ushort h) {
  return __uint_as_float(((unsigned)h) << 16);
}

__device__ __forceinline__ void load8(const float* p, float* o) {
  float4 a = reinterpret_cast<const float4*>(p)[0];
  float4 b = reinterpret_cast<const float4*>(p)[1];
  o[0] = a.x; o[1] = a.y; o[2] = a.z; o[3] = a.w;
  o[4] = b.x; o[5] = b.y; o[6] = b.z; o[7] = b.w;
}

__device__ __forceinline__ void cvt_split(const float* v, short8& h, short8& l) {
#pragma unroll
  for (int j = 0; j < 8; ++j) {
    ushort hb = f2bf(v[j]);
    ushort lb = f2bf(v[j] - bf2f(hb));
    h[j] = (short)hb;
    l[j] = (short)lb;
  }
}

// Blocks 0..15: split Wi[256x128] into MFMA B-fragment planes (hi, lo).
// Block 16: collapsed tail weights Wcc = W1@(W2@Wh), c1 = b1@(W2@Wh),
//           bc = b2@Wh + bh  (stored Wcc[0..255], [256..257], [258..259]).
// Block 17: zero the bucket counters (re-zeroed every graph replay).
__global__ __launch_bounds__(256)
void k_prep(const float* __restrict__ Wi, const float* __restrict__ W1,
            const float* __restrict__ W2, const float* __restrict__ Wh,
            const float* __restrict__ b1, const float* __restrict__ b2,
            const float* __restrict__ bh, ushort* __restrict__ outHi,
            float* __restrict__ Wcc, int* __restrict__ bcnt) {
  __shared__ float Wc2s[DIM_H][2];
  constexpr int CH = DIM_IN / 32;   // 8
  if (blockIdx.x == 17) {
    for (int i = threadIdx.x; i < NBKT * CPAD; i += 256) bcnt[i] = 0;
    return;
  }
  if (blockIdx.x == 16) {
    const int t = threadIdx.x;
    const int i = t >> 1, j = t & 1;
    float s = 0.f;
#pragma unroll 4
    for (int m = 0; m < DIM_H; ++m) s += W2[(size_t)i * DIM_H + m] * Wh[m * 2 + j];
    Wc2s[i][j] = s;
    __syncthreads();
    float c = 0.f;
#pragma unroll 4
    for (int k = 0; k < DIM_H; ++k) c += W1[(size_t)i * DIM_H + k] * Wc2s[k][j];
    Wcc[i * 2 + j] = c;
    if (t < 2) {
      float a = 0.f, b = 0.f;
      for (int k = 0; k < DIM_H; ++k) {
        a += b1[k] * Wc2s[k][t];
        b += b2[k] * Wh[k * 2 + t];
      }
      Wcc[256 + t] = a;           // c1
      Wcc[258 + t] = b + bh[t];   // bc
    }
    return;
  }
  int idx = blockIdx.x * 256 + threadIdx.x;   // < CH*512 = 4096
  int n  = idx & 15;
  int qq = (idx >> 4) & 3;
  int nt = (idx >> 6) & 7;
  int c  = idx >> 9;
  int col = nt * 16 + n;
  short8 h8, l8;
#pragma unroll
  for (int j = 0; j < 8; ++j) {
    float v = Wi[(size_t)(c * 32 + qq * 8 + j) * DIM_H + col];
    ushort hb = f2bf(v);
    ushort lb = f2bf(v - bf2f(hb));
    h8[j] = (short)hb;
    l8[j] = (short)lb;
  }
  ((short8*)outHi)[idx] = h8;
  ((short8*)outHi)[CH * 512 + idx] = l8;
}

// ---------------- single-pass bucket binning (no pre-scan, no 2nd edge read)
// record = src | (d&127)<<17; bucket chunk reserved via one global atomic per
// (block,bucket); records land at ebuf[bkt*CAP + pos], order-free per bucket.
__global__ __launch_bounds__(1024)
void k_bin1(const int* __restrict__ eidx, int* __restrict__ bcnt,
            unsigned* __restrict__ ebuf) {
  __shared__ int hist[NBKT];
  __shared__ int curL[NBKT];
  __shared__ int s_or;
  const int t = threadIdx.x;
  // per-block width detect: int64 input => all high words zero
  if (t == 0) s_or = 0;
  for (int i = t; i < NBKT; i += 1024) hist[i] = 0;
  __syncthreads();
  if (eidx[2 * t + 1] != 0) atomicOr(&s_or, 1);
  __syncthreads();
  const int is64 = (s_or == 0);

  unsigned rec[EPB / 1024];
  int bkt[EPB / 1024];
#pragma unroll
  for (int j = 0; j < EPB / 1024; ++j) {
    int e = blockIdx.x * EPB + j * 1024 + t;
    bkt[j] = -1;
    rec[j] = 0;
    if (e < N_EDGES) {
      unsigned s = (unsigned)get_src(eidx, is64, e);
      unsigned d = (unsigned)get_dst(eidx, is64, e);
      if (s < N_NODES && d < N_NODES) {
        bkt[j] = (int)(d >> 7);
        rec[j] = s | ((d & 127u) << 17);
        atomicAdd(&hist[bkt[j]], 1);
      }
    }
  }
  __syncthreads();
  for (int i = t; i < NBKT; i += 1024) {
    int h = hist[i];
    curL[i] = h ? atomicAdd(&bcnt[i * CPAD], h) : 0;
  }
  __syncthreads();
#pragma unroll
  for (int j = 0; j < EPB / 1024; ++j) {
    if (bkt[j] >= 0) {
      int pos = atomicAdd(&curL[bkt[j]], 1);
      ebuf[(size_t)bkt[j] * CAP + pos] = rec[j];
    }
  }
}

// ---------------- per-bucket degree -> dinv (sequential ebuf read) --------
__global__ __launch_bounds__(256)
void k_dinvB(const int* __restrict__ bcnt, const unsigned* __restrict__ ebuf,
             float* __restrict__ dinv) {
  __shared__ int hist[128];
  const int b = blockIdx.x, t = threadIdx.x;
  if (t < 128) hist[t] = 0;
  __syncthreads();
  const int cnt = bcnt[b * CPAD];
  const unsigned* eb = ebuf + (size_t)b * CAP;
  for (int i = t; i < cnt; i += 256) atomicAdd(&hist[eb[i] >> 17], 1);
  __syncthreads();
  if (t < 128) {
    int node = (b << 7) + t;
    if (node < N_NODES) dinv[node] = rsqrtf(1.0f + (float)hist[t]);
  }
}

// ------------- Cooperative MFMA GEMM, 64-row tile, double-buffered LDS with
// XOR-swizzled staging, one barrier per K-step, A+B register prefetch;
// fused z = relu(.)@Wcc epilogue. Emits tbl[row] = (dinv*z0, dinv*z1, dinv, 0).
template <int K>
__global__ __launch_bounds__(256, 4)
void k_gemm_xz(const float* __restrict__ A, const ushort* __restrict__ Bfrag,
               const float* __restrict__ bias, const float* __restrict__ Wcc,
               const float* __restrict__ dinv, float4* __restrict__ tbl) {
  constexpr int CH = K / 32;   // 8
  __shared__ __align__(16) ushort AhiS[2][256 * 8];
  __shared__ __align__(16) ushort AloS[2][256 * 8];
  const int tid = threadIdx.x;
  const int m0 = blockIdx.x * 64;
  const int wave = tid >> 6, lane = tid & 63;
  const int m_l = lane & 15, quad = lane >> 4;
  const int rs = tid >> 2, q = tid & 3;

  f32x4 acc[2][4];
#pragma unroll
  for (int i = 0; i < 2; ++i)
#pragma unroll
    for (int j = 0; j < 4; ++j) acc[i][j] = (f32x4){0.f, 0.f, 0.f, 0.f};

  const short8* Bhi8 = (const short8*)Bfrag;
  const short8* Blo8 = Bhi8 + CH * 512;
  short8* Ah = (short8*)AhiS;
  short8* Al = (short8*)AloS;

  const int gr = m0 + rs;
  const float* Ap = &A[(size_t)((gr < N_NODES) ? gr : (N_NODES - 1)) * K + q * 8];
  const int went = (rs >> 4) * 64 + q * 16 + ((rs & 15) ^ (q << 2));   // swizzled write
  const int rent = quad * 16 + (m_l ^ (quad << 2));                     // + mt*64 on read

  {
    float v[8];
    load8(Ap, v);
    short8 h, l;
    cvt_split(v, h, l);
    Ah[went] = h;
    Al[went] = l;
  }
  const int bq = quad * 16 + m_l;
  short8 bh0 = Bhi8[(wave * 2 + 0) * 64 + bq];
  short8 bl0 = Blo8[(wave * 2 + 0) * 64 + bq];
  short8 bh1 = Bhi8[(wave * 2 + 1) * 64 + bq];
  short8 bl1 = Blo8[(wave * 2 + 1) * 64 + bq];
  __syncthreads();

#pragma unroll
  for (int c = 0; c < CH; ++c) {
    const int cur = c & 1, nxt = cur ^ 1;
    float vn[8];
    short8 nbh0, nbl0, nbh1, nbl1;
    if (c + 1 < CH) {
      load8(Ap + (c + 1) * 32, vn);
      const int b0 = ((c + 1) * 8 + wave * 2 + 0) * 64 + bq;
      const int b1 = ((c + 1) * 8 + wave * 2 + 1) * 64 + bq;
      nbh0 = Bhi8[b0]; nbl0 = Blo8[b0];
      nbh1 = Bhi8[b1]; nbl1 = Blo8[b1];
    }
    const short8* AhC = Ah + cur * 256;
    const short8* AlC = Al + cur * 256;
#pragma unroll
    for (int mt = 0; mt < 4; ++mt) {
      short8 ahi = AhC[mt * 64 + rent];
      short8 alo = AlC[mt * 64 + rent];
      acc[0][mt] = __builtin_amdgcn_mfma_f32_16x16x32_bf16(ahi, bh0, acc[0][mt], 0, 0, 0);
      acc[0][mt] = __builtin_amdgcn_mfma_f32_16x16x32_bf16(ahi, bl0, acc[0][mt], 0, 0, 0);
      acc[0][mt] = __builtin_amdgcn_mfma_f32_16x16x32_bf16(alo, bh0, acc[0][mt], 0, 0, 0);
      acc[1][mt] = __builtin_amdgcn_mfma_f32_16x16x32_bf16(ahi, bh1, acc[1][mt], 0, 0, 0);
      acc[1][mt] = __builtin_amdgcn_mfma_f32_16x16x32_bf16(ahi, bl1, acc[1][mt], 0, 0, 0);
      acc[1][mt] = __builtin_amdgcn_mfma_f32_16x16x32_bf16(alo, bh1, acc[1][mt], 0, 0, 0);
    }
    if (c + 1 < CH) {
      short8 h, l;
      cvt_split(vn, h, l);
      Ah[nxt * 256 + went] = h;
      Al[nxt * 256 + went] = l;
      bh0 = nbh0; bl0 = nbl0; bh1 = nbh1; bl1 = nbl1;
    }
    __syncthreads();
  }

  // ---- fused epilogue: p = relu(acc + bias) @ Wcc, reduced over 128 cols
  float p0[4][4], p1[4][4];
#pragma unroll
  for (int mt = 0; mt < 4; ++mt)
#pragma unroll
    for (int r = 0; r < 4; ++r) { p0[mt][r] = 0.f; p1[mt][r] = 0.f; }
#pragma unroll
  for (int ntl = 0; ntl < 2; ++ntl) {
    const int colg = (wave * 2 + ntl) * 16 + m_l;
    const float bv = bias[colg];
    const float w0 = Wcc[colg * 2 + 0];
    const float w1 = Wcc[colg * 2 + 1];
#pragma unroll
    for (int mt = 0; mt < 4; ++mt)
#pragma unroll
      for (int r = 0; r < 4; ++r) {
        float hv = fmaxf(acc[ntl][mt][r] + bv, 0.f);   // relu(h1)
        p0[mt][r] += hv * w0;
        p1[mt][r] += hv * w1;
      }
  }
#pragma unroll
  for (int o = 1; o < 16; o <<= 1) {
#pragma unroll
    for (int mt = 0; mt < 4; ++mt)
#pragma unroll
      for (int r = 0; r < 4; ++r) {
        p0[mt][r] += __shfl_xor(p0[mt][r], o);
        p1[mt][r] += __shfl_xor(p1[mt][r], o);
      }
  }
  // cross-wave reduction via LDS (staging dead after final barrier above)
  float* zred = (float*)AhiS;   // [j][wave][quad][mt][r] = [2][4][4][4][4]
  if (m_l == 0) {
#pragma unroll
    for (int mt = 0; mt < 4; ++mt)
#pragma unroll
      for (int r = 0; r < 4; ++r) {
        zred[(((0 * 4 + wave) * 4 + quad) * 4 + mt) * 4 + r] = p0[mt][r];
        zred[(((1 * 4 + wave) * 4 + quad) * 4 + mt) * 4 + r] = p1[mt][r];
      }
  }
  __syncthreads();
  if (tid < 64) {
    const int mt = tid >> 4, qd = (tid >> 2) & 3, r = tid & 3;
    const int rowg = m0 + tid;
    if (rowg < N_NODES) {
      float s0 = 0.f, s1 = 0.f;
#pragma unroll
      for (int w = 0; w < 4; ++w) {
        s0 += zred[(((0 * 4 + w) * 4 + qd) * 4 + mt) * 4 + r];
        s1 += zred[(((1 * 4 + w) * 4 + qd) * 4 + mt) * 4 + r];
      }
      float dn = dinv[rowg];
      tbl[rowg] = make_float4(dn * s0, dn * s1, dn, 0.f);
    }
  }
}

// ---------------- pass 1, bucket-centric: LDS accumulate 3 floats/edge.
// yt[d] = dinv²·(z[d]+Σz[s]); g[d] = dinv·(dinv+Σdinv[s]).
__global__ __launch_bounds__(256)
void k_aggr1B(const int* __restrict__ bcnt, const unsigned* __restrict__ ebuf,
              const float4* __restrict__ tbl, float2* __restrict__ tb2,
              float* __restrict__ g) {
  __shared__ float acc[128][4];
  const int b = blockIdx.x, t = threadIdx.x;
  if (t < 128) { acc[t][0] = 0.f; acc[t][1] = 0.f; acc[t][2] = 0.f; }
  __syncthreads();
  const int cnt = bcnt[b * CPAD];
  const unsigned* eb = ebuf + (size_t)b * CAP;
  for (int i = t; i < cnt; i += 256) {
    unsigned r = eb[i];
    float4 v = tbl[r & 0x1FFFFu];
    int d = r >> 17;
    atomicAdd(&acc[d][0], v.x);
    atomicAdd(&acc[d][1], v.y);
    atomicAdd(&acc[d][2], v.z);
  }
  __syncthreads();
  if (t < 128) {
    int node = (b << 7) + t;
    if (node < N_NODES) {
      float4 self = tbl[node];
      float dn = self.z;
      tb2[node] = make_float2(dn * dn * (acc[t][0] + self.x),
                              dn * dn * (acc[t][1] + self.y));
      g[node] = dn * (acc[t][2] + self.z);
    }
  }
}

// ---------------- pass 2, bucket-centric: out = bc + dinv·(yt+Σyt) + g·c1.
// tail = {c1[0],c1[1],bc[0],bc[1]}
__global__ __launch_bounds__(256)
void k_aggr2B(const int* __restrict__ bcnt, const unsigned* __restrict__ ebuf,
              const float2* __restrict__ tb2, const float4* __restrict__ tbl,
              const float* __restrict__ g, const float* __restrict__ tail,
              float* __restrict__ out) {
  __shared__ float acc[128][2];
  const int b = blockIdx.x, t = threadIdx.x;
  if (t < 128) { acc[t][0] = 0.f; acc[t][1] = 0.f; }
  __syncthreads();
  const int cnt = bcnt[b * CPAD];
  const unsigned* eb = ebuf + (size_t)b * CAP;
  for (int i = t; i < cnt; i += 256) {
    unsigned r = eb[i];
    float2 v = tb2[r & 0x1FFFFu];
    int d = r >> 17;
    atomicAdd(&acc[d][0], v.x);
    atomicAdd(&acc[d][1], v.y);
  }
  __syncthreads();
  if (t < 128) {
    int node = (b << 7) + t;
    if (node < N_NODES) {
      float2 self = tb2[node];
      float dn = tbl[node].z;
      float gv = g[node];
      float o0 = dn * (acc[t][0] + self.x) + gv * tail[0] + tail[2];
      float o1 = dn * (acc[t][1] + self.y) + gv * tail[1] + tail[3];
      reinterpret_cast<float2*>(out)[node] = make_float2(o0, o1);
    }
  }
}

// --------------------------------------------- fp32 fallback (small ws) ----
__global__ __launch_bounds__(1024) void k_detect(const int* __restrict__ e,
                                                 int* __restrict__ flag) {
  __shared__ int s;
  if (threadIdx.x == 0) s = 0;
  __syncthreads();
  atomicOr(&s, e[2 * threadIdx.x + 1]);
  __syncthreads();
  if (threadIdx.x == 0) *flag = (s == 0) ? 1 : 0;
}

__global__ __launch_bounds__(256) void k_zero(int* __restrict__ p, int n) {
  int i = blockIdx.x * 256 + threadIdx.x;
  if (i < n) p[i] = 0;
}

__global__ __launch_bounds__(256) void k_count(const int* __restrict__ eidx,
                                               const int* __restrict__ flag,
                                               int* __restrict__ off) {
  int e = blockIdx.x * 256 + threadIdx.x;
  int is64 = *flag;
  if (e < N_EDGES) {
    unsigned d = (unsigned)get_dst(eidx, is64, e);
    if (d < N_NODES) atomicAdd(&off[d], 1);
  }
}

__global__ __launch_bounds__(256) void k_dinv_old(const int* __restrict__ off,
                                                  float* __restrict__ dinv) {
  int i = blockIdx.x * 256 + threadIdx.x;
  if (i < N_NODES) dinv[i] = rsqrtf(1.0f + (float)off[i]);
}

template <int K>
__global__ __launch_bounds__(256)
void k_gemm(const float* __restrict__ A, const float* __restrict__ B,
            const float* __restrict__ bias, const float* __restrict__ scale,
            float* __restrict__ C, const int do_relu) {
  __shared__ float As[64][33];
  const int tid = threadIdx.x;
  const int tx = tid & 15;
  const int ty = tid >> 4;
  const int m0 = blockIdx.x * 64;

  float acc[4][8];
#pragma unroll
  for (int i = 0; i < 4; ++i)
#pragma unroll
    for (int j = 0; j < 8; ++j) acc[i][j] = 0.f;

  const int rs = tid >> 2;
  const int ks = (tid & 3) * 8;

  for (int k0 = 0; k0 < K; k0 += 32) {
    float av8[8];
    const int gm = m0 + rs;
    if (gm < N_NODES) {
      load8(&A[(size_t)gm * K + k0 + ks], av8);
    } else {
#pragma unroll
      for (int j = 0; j < 8; ++j) av8[j] = 0.f;
    }
    __syncthreads();
#pragma unroll
    for (int j = 0; j < 8; ++j) As[rs][ks + j] = av8[j];
    __syncthreads();

    const float* Bp = B + (size_t)k0 * DIM_H + tx * 8;
#pragma unroll 4
    for (int k = 0; k < 32; ++k) {
      float bv[8];
      load8(Bp + (size_t)k * DIM_H, bv);
      float av[4];
#pragma unroll
      for (int rr = 0; rr < 4; ++rr) av[rr] = As[ty * 4 + rr][k];
#pragma unroll
      for (int rr = 0; rr < 4; ++rr)
#pragma unroll
        for (int cc = 0; cc < 8; ++cc)
          acc[rr][cc] = fmaf(av[rr], bv[cc], acc[rr][cc]);
    }
  }

  float bs[8];
  if (bias) {
    load8(bias + tx * 8, bs);
  } else {
#pragma unroll
    for (int j = 0; j < 8; ++j) bs[j] = 0.f;
  }
#pragma unroll
  for (int rr = 0; rr < 4; ++rr) {
    const int gm = m0 + ty * 4 + rr;
    if (gm < N_NODES) {
      float sc = scale ? scale[gm] : 1.0f;
      float v[8];
#pragma unroll
      for (int cc = 0; cc < 8; ++cc) {
        float t = acc[rr][cc] + bs[cc];
        if (do_relu) t = fmaxf(t, 0.f);
        v[cc] = t * sc;
      }
      float* Cp = &C[(size_t)gm * DIM_H + tx * 8];
      reinterpret_cast<float4*>(Cp)[0] = make_float4(v[0], v[1], v[2], v[3]);
      reinterpret_cast<float4*>(Cp)[1] = make_float4(v[4], v[5], v[6], v[7]);
    }
  }
}

__global__ __launch_bounds__(256)
void k_aggr_init(const float* __restrict__ t, const float* __restrict__ dinv,
                 const float* __restrict__ bias, float* __restrict__ h) {
  int idx = blockIdx.x * 256 + threadIdx.x;
  if (idx < N_NODES * DIM_H) {
    int i = idx >> 7;
    int c = idx & 127;
    float d = dinv[i];
    h[idx] = bias[c] + t[idx] * d * d;
  }
}

__global__ __launch_bounds__(256)
void k_aggr_edges(const int* __restrict__ eidx, const int* __restrict__ flag,
                  const float* __restrict__ t, const float* __restrict__ dinv,
                  float* __restrict__ h) {
  int e = blockIdx.x * 2 + (threadIdx.x >> 7);
  int c = threadIdx.x & 127;
  int is64 = *flag;
  if (e < N_EDGES) {
    unsigned s = (unsigned)get_src(eidx, is64, e);
    unsigned d = (unsigned)get_dst(eidx, is64, e);
    if (s < N_NODES && d < N_NODES) {
      float nrm = dinv[s] * dinv[d];
      unsafeAtomicAdd(&h[(size_t)d * DIM_H + c], t[(size_t)s * DIM_H + c] * nrm);
    }
  }
}

__global__ __launch_bounds__(256)
void k_head_f32(const float* __restrict__ h, const float* __restrict__ Wh,
                const float* __restrict__ bh, float* __restrict__ out) {
  int node = blockIdx.x * 4 + (threadIdx.x >> 6);
  int lane = threadIdx.x & 63;
  if (node >= N_NODES) return;
  float h0 = h[(size_t)node * DIM_H + lane];
  float h1 = h[(size_t)node * DIM_H + 64 + lane];
  float s0 = h0 * Wh[lane * 2 + 0] + h1 * Wh[(lane + 64) * 2 + 0];
  float s1 = h0 * Wh[lane * 2 + 1] + h1 * Wh[(lane + 64) * 2 + 1];
#pragma unroll
  for (int off = 32; off > 0; off >>= 1) {
    s0 += __shfl_down(s0, off);
    s1 += __shfl_down(s1, off);
  }
  if (lane == 0) {
    reinterpret_cast<float2*>(out)[node] = make_float2(s0 + bh[0], s1 + bh[1]);
  }
}

// ---------------------------------------------------------------- launch
extern "C" void kernel_launch(void* const* d_in, const int* in_sizes, int n_in,
                              void* d_out, int out_size, void* d_ws, size_t ws_size,
                              hipStream_t stream) {
  (void)in_sizes; (void)n_in; (void)out_size;
  const int* eidx = (const int*)d_in[0];
  const float* x  = (const float*)d_in[1];
  const float* Wi = (const float*)d_in[2];
  const float* bi = (const float*)d_in[3];
  const float* W1 = (const float*)d_in[4];
  const float* b1 = (const float*)d_in[5];
  const float* W2 = (const float*)d_in[6];
  const float* b2 = (const float*)d_in[7];
  const float* Wh = (const float*)d_in[8];
  const float* bh = (const float*)d_in[9];
  float* out = (float*)d_out;

  const int gE  = (N_EDGES + 255) / 256;
  const int gM  = (N_NODES + 63) / 64;       // 1563
  const int gW  = (N_NODES + 3) / 4;

  char* ws = (char*)d_ws;

  const size_t need1 = 16201600;

  if (ws_size >= need1) {
    float*    Wcc  = (float*)(ws + 4096);       // 260 floats
    ushort*   bfWi = (ushort*)(ws + 8192);      // 131072 B -> 139264
    int*      bcnt = (int*)(ws + 139264);       // 50048 B  -> 189312
    float*    dinv = (float*)(ws + 189312);     // 400000 B -> 589312
    float4*   tbl  = (float4*)(ws + 589312);    // 1600000 B -> 2189312
    float2*   tb2  = (float2*)(ws + 2189312);   // 800000 B -> 2989312
    float*    g    = (float*)(ws + 2989312);    // 400000 B -> 3389312
    unsigned* ebuf = (unsigned*)(ws + 3389312); // 12812288 B -> 16201600

    // weight prep (+bcnt zero, block 17) — no deps, first
    k_prep<<<18, 256, 0, stream>>>(Wi, W1, W2, Wh, b1, b2, bh, bfWi, Wcc, bcnt);
    // single-pass bucket binning: ONE edge-list read, no scan, no csr
    k_bin1<<<NBLK, 1024, 0, stream>>>(eidx, bcnt, ebuf);
    // per-bucket degree -> dinv
    k_dinvB<<<NBKT, 256, 0, stream>>>(bcnt, ebuf, dinv);
    // z = relu(x@Wi+bi) @ Wcc fused into GEMM epilogue -> tbl (N x float4)
    k_gemm_xz<DIM_IN><<<gM, 256, 0, stream>>>(x, bfWi, bi, Wcc, dinv, tbl);
    // bucket-centric aggregations: LDS atomics, L2-resident gathers
    k_aggr1B<<<NBKT, 256, 0, stream>>>(bcnt, ebuf, tbl, tb2, g);
    k_aggr2B<<<NBKT, 256, 0, stream>>>(bcnt, ebuf, tb2, tbl, g, Wcc + 256, out);
  } else {
    // fallback: fp32 atomic-scatter path (~103 MB)
    const int gN  = (N_NODES + 255) / 256;
    int*   flag = (int*)ws;
    int*   off  = (int*)(ws + 4096);
    float* dinv = (float*)(ws + 404480);
    float* fbA  = (float*)(ws + 804864);
    float* fbB  = (float*)(ws + 804864 + (size_t)N_NODES * DIM_H * 4);
    const int gNH = (N_NODES * DIM_H + 255) / 256;
    const int gE2 = (N_EDGES + 1) / 2;
    k_detect<<<1, 1024, 0, stream>>>(eidx, flag);
    k_zero<<<gN, 256, 0, stream>>>(off, N_NODES);
    k_count<<<gE, 256, 0, stream>>>(eidx, flag, off);
    k_dinv_old<<<gN, 256, 0, stream>>>(off, dinv);

    k_gemm<DIM_IN><<<gM, 256, 0, stream>>>(x, Wi, bi, nullptr, fbA, 1);
    k_gemm<DIM_H><<<gM, 256, 0, stream>>>(fbA, W1, nullptr, nullptr, fbB, 0);
    k_aggr_init<<<gNH, 256, 0, stream>>>(fbB, dinv, b1, fbA);
    k_aggr_edges<<<gE2, 256, 0, stream>>>(eidx, flag, fbB, dinv, fbA);
    k_gemm<DIM_H><<<gM, 256, 0, stream>>>(fbA, W2, nullptr, nullptr, fbB, 0);
    k_aggr_init<<<gNH, 256, 0, stream>>>(fbB, dinv, b2, fbA);
    k_aggr_edges<<<gE2, 256, 0, stream>>>(eidx, flag, fbB, dinv, fbA);
    k_head_f32<<<gW, 256, 0, stream>>>(fbA, Wh, bh, out);
  }
}